// Round 6
// baseline (378.590 us; speedup 1.0000x reference)
//
#include <hip/hip_runtime.h>

typedef short short8 __attribute__((ext_vector_type(8)));
typedef float f32x4 __attribute__((ext_vector_type(4)));
typedef unsigned short u16;
typedef u16 u16x8 __attribute__((ext_vector_type(8)));
typedef unsigned int u32;
typedef u32 u32x4 __attribute__((ext_vector_type(4)));

#define NTOK 4096
#define CDIM 256
#define TQ 64
#define TJ 32
#define NT (NTOK / TJ)
#define LOG2E 1.44269504088896f

__device__ __forceinline__ u16 f2bf(float f) {
    unsigned u = __float_as_uint(f);
    unsigned r = (u + 0x7fffu + ((u >> 16) & 1u)) >> 16;   // RNE
    return (u16)r;
}
__device__ __forceinline__ float bf2f(u16 h) { return __uint_as_float(((unsigned)h) << 16); }
__device__ __forceinline__ u32 pk_bf16(float a, float b) {
    u32 w;
    asm("v_cvt_pk_bf16_f32 %0, %1, %2" : "=v"(w) : "v"(a), "v"(b));
    return w;
}

// ---------------------------------------------------------------------------
// W convert: rows 0-31 Wq, 32-63 Wk, 64-319 Wv -> whi/wlo bf16 [320][256]
// ---------------------------------------------------------------------------
__global__ __launch_bounds__(256)
void wconv(const float* __restrict__ Wq, const float* __restrict__ Wk,
           const float* __restrict__ Wv, u16* __restrict__ whi, u16* __restrict__ wlo) {
    const int row = blockIdx.x;
    const int col = threadIdx.x;
    float v;
    if (row < 32)       v = Wq[row * 256 + col];
    else if (row < 64)  v = Wk[(row - 32) * 256 + col];
    else                v = Wv[(row - 64) * 256 + col];
    u16 h = f2bf(v);
    whi[row * 256 + col] = h;
    wlo[row * 256 + col] = f2bf(v - bf2f(h));
}

// ---------------------------------------------------------------------------
// Fused projection via MFMA (hi/lo 3-term). Block: 64 tokens, all 320 out ch.
// ---------------------------------------------------------------------------
__global__ __launch_bounds__(256, 1)
void proj_fused(const float* __restrict__ x,
                const u16* __restrict__ whi, const u16* __restrict__ wlo,
                const float* __restrict__ bq, const float* __restrict__ bk,
                const float* __restrict__ bv,
                u16* __restrict__ qhi, u16* __restrict__ qlo,
                u16* __restrict__ khi, u16* __restrict__ klo,
                u16* __restrict__ vbf) {
    __shared__ __attribute__((aligned(16))) u16 lxh[64][260];
    __shared__ __attribute__((aligned(16))) u16 lxl[64][260];
    const int b  = blockIdx.y;
    const int n0 = blockIdx.x * 64;
    const int t  = threadIdx.x;
    const int w  = t >> 6;
    const int l  = t & 63;
    const int cl = l & 15;
    const int kg = l >> 4;

    const int sn = (t & 15) * 4;
    const int sc = t >> 4;
#pragma unroll
    for (int cc = 0; cc < 16; cc++) {
        const int c = sc + cc * 16;
        const f32x4 xv = *(const f32x4*)&x[((size_t)(b * CDIM + c)) * NTOK + n0 + sn];
#pragma unroll
        for (int i = 0; i < 4; i++) {
            u16 hh = f2bf(xv[i]);
            lxh[sn + i][c] = hh;
            lxl[sn + i][c] = f2bf(xv[i] - bf2f(hh));
        }
    }
    __syncthreads();

    f32x4 acc[5][4];
    const f32x4 fz = {0.f, 0.f, 0.f, 0.f};
#pragma unroll
    for (int i = 0; i < 5; i++)
#pragma unroll
        for (int nt = 0; nt < 4; nt++) acc[i][nt] = fz;

#pragma unroll 2
    for (int ks = 0; ks < 8; ks++) {
        const int k0 = ks * 32;
        short8 bh[4], bl[4];
#pragma unroll
        for (int nt = 0; nt < 4; nt++) {
            bh[nt] = *(const short8*)&lxh[nt * 16 + cl][k0 + kg * 8];
            bl[nt] = *(const short8*)&lxl[nt * 16 + cl][k0 + kg * 8];
        }
#pragma unroll
        for (int i = 0; i < 5; i++) {
            const int mt = w * 5 + i;
            const size_t wb = (size_t)(mt * 16 + cl) * 256 + k0 + kg * 8;
            const short8 ah = *(const short8*)&whi[wb];
            const short8 al = *(const short8*)&wlo[wb];
#pragma unroll
            for (int nt = 0; nt < 4; nt++) {
                acc[i][nt] = __builtin_amdgcn_mfma_f32_16x16x32_bf16(ah, bh[nt], acc[i][nt], 0, 0, 0);
                acc[i][nt] = __builtin_amdgcn_mfma_f32_16x16x32_bf16(ah, bl[nt], acc[i][nt], 0, 0, 0);
                acc[i][nt] = __builtin_amdgcn_mfma_f32_16x16x32_bf16(al, bh[nt], acc[i][nt], 0, 0, 0);
            }
        }
    }

#pragma unroll
    for (int i = 0; i < 5; i++) {
        const int mt = w * 5 + i;
#pragma unroll
        for (int nt = 0; nt < 4; nt++) {
            const int n = n0 + nt * 16 + cl;
#pragma unroll
            for (int r = 0; r < 4; r++) {
                const int m = kg * 4 + r;
                float v = acc[i][nt][r];
                if (mt < 2) {
                    const int ch = mt * 16 + m;
                    v += bq[ch];
                    u16 hh = f2bf(v);
                    qhi[((size_t)(b * NTOK + n)) * 32 + ch] = hh;
                    qlo[((size_t)(b * NTOK + n)) * 32 + ch] = f2bf(v - bf2f(hh));
                } else if (mt < 4) {
                    const int ch = (mt - 2) * 16 + m;
                    v += bk[ch];
                    khi[((size_t)(b * NTOK + n)) * 32 + ch] = f2bf(v);
                } else {
                    const int c2 = (mt - 4) * 16 + m;
                    vbf[((size_t)(b * CDIM + c2)) * NTOK + n] = f2bf(v + bv[c2]);
                }
            }
        }
    }
}

// ---------------------------------------------------------------------------
// Fused flash attention, producer/consumer wave split.
// 512-thread block (8 waves), grid 256 (1/CU). TQ=64 queries, full 256 c.
//   waves 0-3 (producers): QK^T (swapped, K single bf16 + Q hi/lo), in-lane
//     softmax, defer-max, bpermute -> P B-frag, write P+f to LDS.
//   waves 4-7 (consumers): 64-c slice x 4 q-tiles PV MFMAs, rescale via f.
// Skewed pipeline: PV_{t-1} runs concurrent with P_t. V triple-buffered,
// K/P double-buffered, ONE barrier per iteration.
// ---------------------------------------------------------------------------
__global__ __launch_bounds__(512, 1)
void attn_mfma(const u16* __restrict__ qhi, const u16* __restrict__ qlo,
               const u16* __restrict__ khi, const u16* __restrict__ vbf,
               const float* __restrict__ x, float* __restrict__ out) {
    __shared__ __attribute__((aligned(16))) u16 lv[3][CDIM][TJ];   // 48 KB
    __shared__ __attribute__((aligned(16))) u16 lk[2][TJ][32];     // 4 KB
    __shared__ __attribute__((aligned(16))) u32 lp[2][4][256];     // 8 KB
    __shared__ float lfx[2][4][16];
    __shared__ float lsc[4][16];
    __shared__ __attribute__((aligned(16))) float lt[4][16][20];

    // XCD decode: b fixed per XCD pair -> K/V[b] resident in L2
    const int lin = blockIdx.x;
    const int b  = (lin >> 1) & 3;
    const int qb = ((lin & 1) << 5) | (lin >> 3);
    const int i0 = qb * TQ;
    const int t  = threadIdx.x;
    const int w  = t >> 6;
    const int l  = t & 63;
    const int cl = l & 15;
    const int kg = l >> 4;
    const bool producer = (w < 4);

    // producer Q B-fragments (q-tile = w)
    const int iq = i0 + (w & 3) * 16 + cl;
    short8 qh = {}, ql = {};
    if (producer) {
        qh = *(const short8*)&qhi[((size_t)(b * NTOK + iq)) * 32 + kg * 8];
        ql = *(const short8*)&qlo[((size_t)(b * NTOK + iq)) * 32 + kg * 8];
    }

    // staging: V all 512 threads (256 c-rows, 2 chunks each), K threads 0-127
    const int vc   = t & 255;
    const int vch0 = (t >> 8) * 2;
    const u16* vsrc = &vbf[((size_t)(b * CDIM + vc)) * NTOK + vch0 * 8];
    const int kj  = t >> 2;
    const int kch = t & 3;
    const u16* ksrc = &khi[((size_t)(b * NTOK + kj)) * 32 + kch * 8];

    u16x8 vr0, vr1, kr;
    auto stage_load = [&](int tt) {
        const int j0 = tt * TJ;
        vr0 = *(const u16x8*)&vsrc[j0];
        vr1 = *(const u16x8*)&vsrc[j0 + 8];
        if (t < 128) kr = *(const u16x8*)&ksrc[(size_t)j0 * 32];
    };
    auto stage_write = [&](int vbuf, int kbuf) {
        const int sw = (vc >> 2) & 3;
        *(u16x8*)&lv[vbuf][vc][((vch0)     ^ sw) * 8] = vr0;
        *(u16x8*)&lv[vbuf][vc][((vch0 + 1) ^ sw) * 8] = vr1;
        if (t < 128) {
            const int ph = kch ^ ((kj >> 2) & 3);
            *(u16x8*)&lk[kbuf][kj][ph * 8] = kr;
        }
    };

    f32x4 acc[4][4];   // consumers: [ct][qt]
    const f32x4 fz = {0.f, 0.f, 0.f, 0.f};
#pragma unroll
    for (int ct = 0; ct < 4; ct++)
#pragma unroll
        for (int qt = 0; qt < 4; qt++) acc[ct][qt] = fz;

    float m_r = -1.0e30f, l_r = 0.f;     // producers

    const int a0 = (((kg << 1) & 3) * 16 + cl) * 4;
    const int a1 = ((((kg << 1) + 1) & 3) * 16 + cl) * 4;
    const bool lo2 = (kg < 2);
    const int cbase = (w & 3) * 64;      // consumer c-slice

    stage_load(0);
    stage_write(0, 0);
    __syncthreads();

    int vwr = 1;   // V buf for tile tt+1
    int vrd = 0;   // V buf for tile tt-1

    for (int tt = 0; tt <= NT; ++tt) {
        const bool haveNext = (tt + 1 < NT);
        if (haveNext) stage_load(tt + 1);

        if (producer) {
            if (tt < NT) {
                const int cur = tt & 1;
                // ---- scores (swapped): St[j][q], lane q=cl
                f32x4 s0 = fz, s1 = fz;
                {
                    const int ph0 = (kg ^ ((cl >> 2) & 3)) * 8;
                    short8 kh = *(const short8*)&lk[cur][cl][ph0];
                    s0 = __builtin_amdgcn_mfma_f32_16x16x32_bf16(kh, qh, s0, 0, 0, 0);
                    s0 = __builtin_amdgcn_mfma_f32_16x16x32_bf16(kh, ql, s0, 0, 0, 0);
                }
                {
                    const int j1 = 16 + cl;
                    const int ph1 = (kg ^ ((j1 >> 2) & 3)) * 8;
                    short8 kh = *(const short8*)&lk[cur][j1][ph1];
                    s1 = __builtin_amdgcn_mfma_f32_16x16x32_bf16(kh, qh, s1, 0, 0, 0);
                    s1 = __builtin_amdgcn_mfma_f32_16x16x32_bf16(kh, ql, s1, 0, 0, 0);
                }

                // ---- in-lane softmax
                float tmax = fmaxf(fmaxf(fmaxf(s0[0], s0[1]), fmaxf(s0[2], s0[3])),
                                   fmaxf(fmaxf(s1[0], s1[1]), fmaxf(s1[2], s1[3])));
                tmax = fmaxf(tmax, __shfl_xor(tmax, 16));
                tmax = fmaxf(tmax, __shfl_xor(tmax, 32));

                float f_r = 1.f;
                if (__any(tmax > m_r + 8.f)) {      // defer-max rescale event
                    float mn = fmaxf(m_r, tmax);
                    f_r = exp2f((m_r - mn) * LOG2E);
                    m_r = mn;
                }
                const float mm = m_r * LOG2E;
                float p00 = exp2f(fmaf(s0[0], LOG2E, -mm));
                float p01 = exp2f(fmaf(s0[1], LOG2E, -mm));
                float p02 = exp2f(fmaf(s0[2], LOG2E, -mm));
                float p03 = exp2f(fmaf(s0[3], LOG2E, -mm));
                float p10 = exp2f(fmaf(s1[0], LOG2E, -mm));
                float p11 = exp2f(fmaf(s1[1], LOG2E, -mm));
                float p12 = exp2f(fmaf(s1[2], LOG2E, -mm));
                float p13 = exp2f(fmaf(s1[3], LOG2E, -mm));
                const float psum = ((p00 + p01) + (p02 + p03)) + ((p10 + p11) + (p12 + p13));
                l_r = l_r * f_r + psum;             // per-lane partial

                // ---- pack + exchange to B-fragment (verified path)
                u32 w0 = pk_bf16(p00, p01);
                u32 w1 = pk_bf16(p02, p03);
                u32 w2 = pk_bf16(p10, p11);
                u32 w3 = pk_bf16(p12, p13);
                u32 y0a = __builtin_amdgcn_ds_bpermute(a0, w0);
                u32 y0b = __builtin_amdgcn_ds_bpermute(a0, w2);
                u32 y1a = __builtin_amdgcn_ds_bpermute(a0, w1);
                u32 y1b = __builtin_amdgcn_ds_bpermute(a0, w3);
                u32 y2a = __builtin_amdgcn_ds_bpermute(a1, w0);
                u32 y2b = __builtin_amdgcn_ds_bpermute(a1, w2);
                u32 y3a = __builtin_amdgcn_ds_bpermute(a1, w1);
                u32 y3b = __builtin_amdgcn_ds_bpermute(a1, w3);
                u32x4 bw;
                bw[0] = lo2 ? y0a : y0b;
                bw[1] = lo2 ? y1a : y1b;
                bw[2] = lo2 ? y2a : y2b;
                bw[3] = lo2 ? y3a : y3b;
                *(u32x4*)&lp[cur][w][l * 4] = bw;
                if (kg == 0) lfx[cur][w][cl] = f_r;
            }
        } else {
            if (tt > 0) {
                const int pc = (tt - 1) & 1;
                // ---- rescale from producer f-values
                float fq0 = lfx[pc][0][cl];
                float fq1 = lfx[pc][1][cl];
                float fq2 = lfx[pc][2][cl];
                float fq3 = lfx[pc][3][cl];
                const bool ok = (fq0 == 1.f) & (fq1 == 1.f) & (fq2 == 1.f) & (fq3 == 1.f);
                if (!__all(ok)) {
#pragma unroll
                    for (int ct = 0; ct < 4; ct++) {
                        acc[ct][0] *= fq0;
                        acc[ct][1] *= fq1;
                        acc[ct][2] *= fq2;
                        acc[ct][3] *= fq3;
                    }
                }
                // ---- PV: V A-frags (this wave's c-slice) x 4 P B-frags
                short8 pf[4];
#pragma unroll
                for (int qt = 0; qt < 4; qt++)
                    pf[qt] = __builtin_bit_cast(short8, *(const u32x4*)&lp[pc][qt][l * 4]);
#pragma unroll
                for (int ct = 0; ct < 4; ct++) {
                    const int row = cbase + ct * 16 + cl;
                    const int ph  = (kg ^ ((row >> 2) & 3)) * 8;
                    short8 vb = *(const short8*)&lv[vrd][row][ph];
#pragma unroll
                    for (int qt = 0; qt < 4; qt++)
                        acc[ct][qt] = __builtin_amdgcn_mfma_f32_16x16x32_bf16(vb, pf[qt], acc[ct][qt], 0, 0, 0);
                }
                vrd = (vrd == 2) ? 0 : vrd + 1;
            }
        }

        if (haveNext) {
            stage_write(vwr, (tt + 1) & 1);
            vwr = (vwr == 2) ? 0 : vwr + 1;
        }
        __syncthreads();
    }

    // ---- l finalize (producers), then consumer epilogue
    if (producer) {
        l_r += __shfl_xor(l_r, 16);
        l_r += __shfl_xor(l_r, 32);
        if (kg == 0) lsc[w][cl] = l_r;
    }
    __syncthreads();

    float linv[4];
    if (!producer) {
#pragma unroll
        for (int qt = 0; qt < 4; qt++) linv[qt] = 1.f / lsc[qt][cl];
    }
    const int cw  = w & 3;
    const int c_r = l >> 2;
    const int q0  = (l & 3) * 4;
#pragma unroll 1
    for (int ct = 0; ct < 4; ct++) {
#pragma unroll 1
        for (int qt = 0; qt < 4; qt++) {
            if (!producer) {
#pragma unroll
                for (int r = 0; r < 4; r++)
                    lt[cw][kg * 4 + r][cl] = acc[ct][qt][r] * linv[qt];
            }
            __syncthreads();
            if (!producer) {
                const f32x4 vv = *(const f32x4*)&lt[cw][c_r][q0];
                const int c = cbase + ct * 16 + c_r;
                const size_t base = ((size_t)(b * CDIM + c)) * NTOK + i0 + qt * 16 + q0;
                const f32x4 xv = *(const f32x4*)&x[base];
                f32x4 o;
#pragma unroll
                for (int ii = 0; ii < 4; ii++) o[ii] = vv[ii] + xv[ii];
                *(f32x4*)&out[base] = o;
            }
            __syncthreads();
        }
    }
}

// ---------------------------------------------------------------------------
extern "C" void kernel_launch(void* const* d_in, const int* in_sizes, int n_in,
                              void* d_out, int out_size, void* d_ws, size_t ws_size,
                              hipStream_t stream) {
    const float* x  = (const float*)d_in[0];
    const float* Wq = (const float*)d_in[1];
    const float* bq = (const float*)d_in[2];
    const float* Wk = (const float*)d_in[3];
    const float* bk = (const float*)d_in[4];
    const float* Wv = (const float*)d_in[5];
    const float* bv = (const float*)d_in[6];
    float* out = (float*)d_out;

    u16* qhi = (u16*)d_ws;                              // [4][4096][32]
    u16* qlo = qhi + (size_t)4 * NTOK * 32;
    u16* khi = qlo + (size_t)4 * NTOK * 32;
    u16* klo = khi + (size_t)4 * NTOK * 32;             // unused by attn now
    u16* vbf = klo + (size_t)4 * NTOK * 32;             // [4][256][4096]
    u16* whi = vbf + (size_t)4 * CDIM * NTOK;           // [320][256]
    u16* wlo = whi + (size_t)320 * 256;

    wconv<<<dim3(320), 256, 0, stream>>>(Wq, Wk, Wv, whi, wlo);
    proj_fused<<<dim3(64, 4), 256, 0, stream>>>(x, whi, wlo, bq, bk, bv,
                                                qhi, qlo, khi, klo, vbf);
    attn_mfma<<<dim3(256), 512, 0, stream>>>(qhi, qlo, khi, vbf, x, out);
}

// Round 7
// 166.537 us; speedup vs baseline: 2.2733x; 2.2733x over previous
//
#include <hip/hip_runtime.h>

typedef short short8 __attribute__((ext_vector_type(8)));
typedef float f32x4 __attribute__((ext_vector_type(4)));
typedef unsigned short u16;
typedef u16 u16x8 __attribute__((ext_vector_type(8)));
typedef unsigned int u32;
typedef u32 u32x2 __attribute__((ext_vector_type(2)));
typedef u32 u32x4 __attribute__((ext_vector_type(4)));

#define NTOK 4096
#define CDIM 256
#define TQ 64
#define TJ 32
#define NT (NTOK / TJ)
#define LOG2E 1.44269504088896f

__device__ __forceinline__ u16 f2bf(float f) {
    unsigned u = __float_as_uint(f);
    unsigned r = (u + 0x7fffu + ((u >> 16) & 1u)) >> 16;   // RNE
    return (u16)r;
}
__device__ __forceinline__ float bf2f(u16 h) { return __uint_as_float(((unsigned)h) << 16); }
__device__ __forceinline__ u32 pk_bf16(float a, float b) {
    u32 w;
    asm("v_cvt_pk_bf16_f32 %0, %1, %2" : "=v"(w) : "v"(a), "v"(b));
    return w;
}

// ---------------------------------------------------------------------------
// W convert: rows 0-31 Wq, 32-63 Wk, 64-319 Wv -> whi/wlo bf16 [320][256]
// ---------------------------------------------------------------------------
__global__ __launch_bounds__(256)
void wconv(const float* __restrict__ Wq, const float* __restrict__ Wk,
           const float* __restrict__ Wv, u16* __restrict__ whi, u16* __restrict__ wlo) {
    const int row = blockIdx.x;
    const int col = threadIdx.x;
    float v;
    if (row < 32)       v = Wq[row * 256 + col];
    else if (row < 64)  v = Wk[(row - 32) * 256 + col];
    else                v = Wv[(row - 64) * 256 + col];
    u16 h = f2bf(v);
    whi[row * 256 + col] = h;
    wlo[row * 256 + col] = f2bf(v - bf2f(h));
}

// ---------------------------------------------------------------------------
// Fused projection via MFMA (hi/lo 3-term). Block: 64 tokens, all 320 out ch.
// Wave w owns m-tiles 5w..5w+4 (mt 0-1=Q, 2-3=K, 4-19=V), 4 n-tiles.
// ---------------------------------------------------------------------------
__global__ __launch_bounds__(256, 1)
void proj_fused(const float* __restrict__ x,
                const u16* __restrict__ whi, const u16* __restrict__ wlo,
                const float* __restrict__ bq, const float* __restrict__ bk,
                const float* __restrict__ bv,
                u16* __restrict__ qhi, u16* __restrict__ qlo,
                u16* __restrict__ khi, u16* __restrict__ klo,
                u16* __restrict__ vbf) {
    __shared__ __attribute__((aligned(16))) u16 lxh[64][260];
    __shared__ __attribute__((aligned(16))) u16 lxl[64][260];
    const int b  = blockIdx.y;
    const int n0 = blockIdx.x * 64;
    const int t  = threadIdx.x;
    const int w  = t >> 6;
    const int l  = t & 63;
    const int cl = l & 15;
    const int kg = l >> 4;

    const int sn = (t & 15) * 4;
    const int sc = t >> 4;
#pragma unroll
    for (int cc = 0; cc < 16; cc++) {
        const int c = sc + cc * 16;
        const f32x4 xv = *(const f32x4*)&x[((size_t)(b * CDIM + c)) * NTOK + n0 + sn];
#pragma unroll
        for (int i = 0; i < 4; i++) {
            u16 hh = f2bf(xv[i]);
            lxh[sn + i][c] = hh;
            lxl[sn + i][c] = f2bf(xv[i] - bf2f(hh));
        }
    }
    __syncthreads();

    f32x4 acc[5][4];
    const f32x4 fz = {0.f, 0.f, 0.f, 0.f};
#pragma unroll
    for (int i = 0; i < 5; i++)
#pragma unroll
        for (int nt = 0; nt < 4; nt++) acc[i][nt] = fz;

#pragma unroll 2
    for (int ks = 0; ks < 8; ks++) {
        const int k0 = ks * 32;
        short8 bh[4], bl[4];
#pragma unroll
        for (int nt = 0; nt < 4; nt++) {
            bh[nt] = *(const short8*)&lxh[nt * 16 + cl][k0 + kg * 8];
            bl[nt] = *(const short8*)&lxl[nt * 16 + cl][k0 + kg * 8];
        }
#pragma unroll
        for (int i = 0; i < 5; i++) {
            const int mt = w * 5 + i;
            const size_t wb = (size_t)(mt * 16 + cl) * 256 + k0 + kg * 8;
            const short8 ah = *(const short8*)&whi[wb];
            const short8 al = *(const short8*)&wlo[wb];
#pragma unroll
            for (int nt = 0; nt < 4; nt++) {
                acc[i][nt] = __builtin_amdgcn_mfma_f32_16x16x32_bf16(ah, bh[nt], acc[i][nt], 0, 0, 0);
                acc[i][nt] = __builtin_amdgcn_mfma_f32_16x16x32_bf16(ah, bl[nt], acc[i][nt], 0, 0, 0);
                acc[i][nt] = __builtin_amdgcn_mfma_f32_16x16x32_bf16(al, bh[nt], acc[i][nt], 0, 0, 0);
            }
        }
    }

#pragma unroll
    for (int i = 0; i < 5; i++) {
        const int mt = w * 5 + i;
#pragma unroll
        for (int nt = 0; nt < 4; nt++) {
            const int n = n0 + nt * 16 + cl;
#pragma unroll
            for (int r = 0; r < 4; r++) {
                const int m = kg * 4 + r;
                float v = acc[i][nt][r];
                if (mt < 2) {
                    const int ch = mt * 16 + m;
                    v += bq[ch];
                    u16 hh = f2bf(v);
                    qhi[((size_t)(b * NTOK + n)) * 32 + ch] = hh;
                    qlo[((size_t)(b * NTOK + n)) * 32 + ch] = f2bf(v - bf2f(hh));
                } else if (mt < 4) {
                    const int ch = (mt - 2) * 16 + m;
                    v += bk[ch];
                    u16 hh = f2bf(v);
                    khi[((size_t)(b * NTOK + n)) * 32 + ch] = hh;
                    klo[((size_t)(b * NTOK + n)) * 32 + ch] = f2bf(v - bf2f(hh));
                } else {
                    const int c2 = (mt - 4) * 16 + m;
                    vbf[((size_t)(b * CDIM + c2)) * NTOK + n] = f2bf(v + bv[c2]);
                }
            }
        }
    }
}

// ---------------------------------------------------------------------------
// Fused flash attention (round-4 structure + LDS P-exchange).
// Block = 4 waves, TQ=64 queries, ONE HALF (h) of the 256 channels.
// Wave w: q-tile w (16 q), 128 c. Grid 512 -> 2 independent blocks/CU.
//   St[j][q] = mfma(A=K, B=Q), 3-term hi/lo; in-lane softmax; defer-max.
//   P exchange via per-wave LDS pair buffer: 2x ds_write_b64 + 1x ds_read_b128
//   PV: D[c][q] = mfma(A=V, B=P), 8 c-tiles (acc[8] = 32 VGPR, no spill)
// ---------------------------------------------------------------------------
__global__ __launch_bounds__(256, 2)
void attn_mfma(const u16* __restrict__ qhi, const u16* __restrict__ qlo,
               const u16* __restrict__ khi, const u16* __restrict__ klo,
               const u16* __restrict__ vbf, const float* __restrict__ x,
               float* __restrict__ out) {
    __shared__ __attribute__((aligned(16))) u16 lkh[2][TJ][32];
    __shared__ __attribute__((aligned(16))) u16 lkl[2][TJ][32];
    __shared__ __attribute__((aligned(16))) u16 lv[2][128][TJ];
    __shared__ __attribute__((aligned(16))) u32 lp[4][16][20];   // per-wave P pairs
    __shared__ __attribute__((aligned(16))) float lt[4][16][20];

    // XCD decode: (b,h) fixed per XCD -> V-half (1MB) + K resident in that L2
    const int lin = blockIdx.x;
    const int p  = lin & 7;
    const int b  = p >> 1;
    const int h  = p & 1;
    const int qb = lin >> 3;
    const int i0 = qb * TQ;
    const int t  = threadIdx.x;
    const int w  = t >> 6;
    const int l  = t & 63;
    const int cl = l & 15;
    const int kg = l >> 4;

    // Q B-fragments
    const int iq = i0 + w * 16 + cl;
    const short8 qh = *(const short8*)&qhi[((size_t)(b * NTOK + iq)) * 32 + kg * 8];
    const short8 ql = *(const short8*)&qlo[((size_t)(b * NTOK + iq)) * 32 + kg * 8];

    // staging sources: V half (128 rows, 2 chunks/thread), K hi/lo
    const int vc   = t & 127;
    const int vch0 = (t >> 7) * 2;
    const u16* vsrc = &vbf[((size_t)(b * CDIM + h * 128 + vc)) * NTOK + vch0 * 8];
    const int kj  = (t & 127) >> 2;
    const int kch = t & 3;
    const u16* ksrcbase = (t < 128) ? khi : klo;
    const u16* ksrc = &ksrcbase[((size_t)(b * NTOK + kj)) * 32 + kch * 8];

    u16x8 vreg0, vreg1, kreg;

    auto stage_load = [&](int tt) {
        const int j0 = tt * TJ;
        vreg0 = *(const u16x8*)&vsrc[j0];
        vreg1 = *(const u16x8*)&vsrc[j0 + 8];
        kreg  = *(const u16x8*)&ksrc[(size_t)j0 * 32];
    };
    auto stage_write = [&](int buf) {
        const int sw = (vc >> 2) & 3;
        *(u16x8*)&lv[buf][vc][((vch0)     ^ sw) * 8] = vreg0;
        *(u16x8*)&lv[buf][vc][((vch0 + 1) ^ sw) * 8] = vreg1;
        int ph = kch ^ ((kj >> 2) & 3);
        u16* kd = (t < 128) ? &lkh[buf][kj][ph * 8] : &lkl[buf][kj][ph * 8];
        *(u16x8*)kd = kreg;
    };

    f32x4 acc[8];   // D[c][q]: local c-row = ct*16 + kg*4 + r, q = cl
    const f32x4 fz = {0.f, 0.f, 0.f, 0.f};
#pragma unroll
    for (int ct = 0; ct < 8; ct++) acc[ct] = fz;

    float m_r = -1.0e30f, l_r = 0.f;   // l_r: per-lane partial (reduced at end)

    stage_load(0);
    stage_write(0);
    __syncthreads();

#pragma unroll 2
    for (int tt = 0; tt < NT; ++tt) {
        const int cur = tt & 1;
        const int nxt = cur ^ 1;
        const bool pre = (tt + 1 < NT);
        if (pre) stage_load(tt + 1);   // issue global loads early (T14)

        // ---- scores (swapped): St[j][q], lane q=cl, rows j=kg*4+r (+16*jt)
        f32x4 s0 = fz, s1 = fz;
        {
            const int j0r = cl;
            const int ph0 = (kg ^ ((j0r >> 2) & 3)) * 8;
            short8 kh = *(const short8*)&lkh[cur][j0r][ph0];
            short8 kl = *(const short8*)&lkl[cur][j0r][ph0];
            s0 = __builtin_amdgcn_mfma_f32_16x16x32_bf16(kh, qh, s0, 0, 0, 0);
            s0 = __builtin_amdgcn_mfma_f32_16x16x32_bf16(kl, qh, s0, 0, 0, 0);
            s0 = __builtin_amdgcn_mfma_f32_16x16x32_bf16(kh, ql, s0, 0, 0, 0);
        }
        {
            const int j1r = 16 + cl;
            const int ph1 = (kg ^ ((j1r >> 2) & 3)) * 8;
            short8 kh = *(const short8*)&lkh[cur][j1r][ph1];
            short8 kl = *(const short8*)&lkl[cur][j1r][ph1];
            s1 = __builtin_amdgcn_mfma_f32_16x16x32_bf16(kh, qh, s1, 0, 0, 0);
            s1 = __builtin_amdgcn_mfma_f32_16x16x32_bf16(kl, qh, s1, 0, 0, 0);
            s1 = __builtin_amdgcn_mfma_f32_16x16x32_bf16(kh, ql, s1, 0, 0, 0);
        }

        // ---- in-lane softmax (per-lane q = cl)
        float tmax = fmaxf(fmaxf(fmaxf(s0[0], s0[1]), fmaxf(s0[2], s0[3])),
                           fmaxf(fmaxf(s1[0], s1[1]), fmaxf(s1[2], s1[3])));
        tmax = fmaxf(tmax, __shfl_xor(tmax, 16));
        tmax = fmaxf(tmax, __shfl_xor(tmax, 32));

        if (__any(tmax > m_r + 8.f)) {          // defer-max rescale event
            float mn = fmaxf(m_r, tmax);
            float f  = exp2f((m_r - mn) * LOG2E);
            m_r = mn;
            l_r *= f;
#pragma unroll
            for (int ct = 0; ct < 8; ct++) acc[ct] *= f;
        }
        const float mm = m_r * LOG2E;
        float p00 = exp2f(fmaf(s0[0], LOG2E, -mm));
        float p01 = exp2f(fmaf(s0[1], LOG2E, -mm));
        float p02 = exp2f(fmaf(s0[2], LOG2E, -mm));
        float p03 = exp2f(fmaf(s0[3], LOG2E, -mm));
        float p10 = exp2f(fmaf(s1[0], LOG2E, -mm));
        float p11 = exp2f(fmaf(s1[1], LOG2E, -mm));
        float p12 = exp2f(fmaf(s1[2], LOG2E, -mm));
        float p13 = exp2f(fmaf(s1[3], LOG2E, -mm));
        l_r += ((p00 + p01) + (p02 + p03)) + ((p10 + p11) + (p12 + p13));

        // ---- P exchange via per-wave LDS pair buffer (same-wave, no barrier)
        // lane (q=cl, kg) holds j-pairs m: w0->m=2kg, w1->m=2kg+1,
        //                                 w2->m=8+2kg, w3->m=8+2kg+1
        // B-frag lane (cl, kg) reads m = 4kg..4kg+3 of row cl.
        u32x2 wa, wb;
        wa[0] = pk_bf16(p00, p01);
        wa[1] = pk_bf16(p02, p03);
        wb[0] = pk_bf16(p10, p11);
        wb[1] = pk_bf16(p12, p13);
        *(u32x2*)&lp[w][cl][2 * kg]     = wa;
        *(u32x2*)&lp[w][cl][8 + 2 * kg] = wb;
        const u32x4 bw = *(const u32x4*)&lp[w][cl][4 * kg];
        const short8 pfrag = __builtin_bit_cast(short8, bw);

        // ---- PV over this block's c-half: 8 c-tiles
#pragma unroll
        for (int ct = 0; ct < 8; ct++) {
            const int row = ct * 16 + cl;
            const int ph  = (kg ^ ((row >> 2) & 3)) * 8;
            short8 vb = *(const short8*)&lv[cur][row][ph];
            acc[ct] = __builtin_amdgcn_mfma_f32_16x16x32_bf16(vb, pfrag, acc[ct], 0, 0, 0);
        }

        if (pre) stage_write(nxt);
        __syncthreads();
    }

    // ---- reduce l across the 4 lane-groups, then epilogue
    l_r += __shfl_xor(l_r, 16);
    l_r += __shfl_xor(l_r, 32);
    const float linv = 1.f / l_r;
    const int c_r = l >> 2;
    const int q0  = (l & 3) * 4;
#pragma unroll
    for (int ct = 0; ct < 8; ct++) {
#pragma unroll
        for (int r = 0; r < 4; r++)
            lt[w][kg * 4 + r][cl] = acc[ct][r] * linv;
        __syncthreads();
        const f32x4 vv = *(const f32x4*)&lt[w][c_r][q0];
        const int c = h * 128 + ct * 16 + c_r;
        const size_t base = ((size_t)(b * CDIM + c)) * NTOK + i0 + w * 16 + q0;
        const f32x4 xv = *(const f32x4*)&x[base];
        f32x4 o;
#pragma unroll
        for (int ii = 0; ii < 4; ii++) o[ii] = vv[ii] + xv[ii];
        *(f32x4*)&out[base] = o;
        __syncthreads();
    }
}

// ---------------------------------------------------------------------------
extern "C" void kernel_launch(void* const* d_in, const int* in_sizes, int n_in,
                              void* d_out, int out_size, void* d_ws, size_t ws_size,
                              hipStream_t stream) {
    const float* x  = (const float*)d_in[0];
    const float* Wq = (const float*)d_in[1];
    const float* bq = (const float*)d_in[2];
    const float* Wk = (const float*)d_in[3];
    const float* bk = (const float*)d_in[4];
    const float* Wv = (const float*)d_in[5];
    const float* bv = (const float*)d_in[6];
    float* out = (float*)d_out;

    u16* qhi = (u16*)d_ws;                              // [4][4096][32]
    u16* qlo = qhi + (size_t)4 * NTOK * 32;
    u16* khi = qlo + (size_t)4 * NTOK * 32;
    u16* klo = khi + (size_t)4 * NTOK * 32;
    u16* vbf = klo + (size_t)4 * NTOK * 32;             // [4][256][4096]
    u16* whi = vbf + (size_t)4 * CDIM * NTOK;           // [320][256]
    u16* wlo = whi + (size_t)320 * 256;

    wconv<<<dim3(320), 256, 0, stream>>>(Wq, Wk, Wv, whi, wlo);
    proj_fused<<<dim3(64, 4), 256, 0, stream>>>(x, whi, wlo, bq, bk, bv,
                                                qhi, qlo, khi, klo, vbf);
    attn_mfma<<<dim3(512), 256, 0, stream>>>(qhi, qlo, khi, klo, vbf, x, out);
}

// Round 8
// 159.427 us; speedup vs baseline: 2.3747x; 1.0446x over previous
//
#include <hip/hip_runtime.h>

typedef short short8 __attribute__((ext_vector_type(8)));
typedef float f32x4 __attribute__((ext_vector_type(4)));
typedef unsigned short u16;
typedef u16 u16x8 __attribute__((ext_vector_type(8)));
typedef unsigned int u32;
typedef u32 u32x2 __attribute__((ext_vector_type(2)));
typedef u32 u32x4 __attribute__((ext_vector_type(4)));

#define NTOK 4096
#define CDIM 256
#define TQ 64
#define TJ 64
#define NT (NTOK / TJ)
#define LOG2E 1.44269504088896f

__device__ __forceinline__ u16 f2bf(float f) {
    unsigned u = __float_as_uint(f);
    unsigned r = (u + 0x7fffu + ((u >> 16) & 1u)) >> 16;   // RNE
    return (u16)r;
}
__device__ __forceinline__ float bf2f(u16 h) { return __uint_as_float(((unsigned)h) << 16); }
__device__ __forceinline__ u32 pk_bf16(float a, float b) {
    u32 w;
    asm("v_cvt_pk_bf16_f32 %0, %1, %2" : "=v"(w) : "v"(a), "v"(b));
    return w;
}

// ---------------------------------------------------------------------------
// W convert: rows 0-31 Wq, 32-63 Wk, 64-319 Wv -> whi/wlo bf16 [320][256]
// ---------------------------------------------------------------------------
__global__ __launch_bounds__(256)
void wconv(const float* __restrict__ Wq, const float* __restrict__ Wk,
           const float* __restrict__ Wv, u16* __restrict__ whi, u16* __restrict__ wlo) {
    const int row = blockIdx.x;
    const int col = threadIdx.x;
    float v;
    if (row < 32)       v = Wq[row * 256 + col];
    else if (row < 64)  v = Wk[(row - 32) * 256 + col];
    else                v = Wv[(row - 64) * 256 + col];
    u16 h = f2bf(v);
    whi[row * 256 + col] = h;
    wlo[row * 256 + col] = f2bf(v - bf2f(h));
}

// ---------------------------------------------------------------------------
// Fused projection via MFMA (hi/lo 3-term). Block: 64 tokens, all 320 out ch.
// ---------------------------------------------------------------------------
__global__ __launch_bounds__(256, 1)
void proj_fused(const float* __restrict__ x,
                const u16* __restrict__ whi, const u16* __restrict__ wlo,
                const float* __restrict__ bq, const float* __restrict__ bk,
                const float* __restrict__ bv,
                u16* __restrict__ qhi, u16* __restrict__ qlo,
                u16* __restrict__ khi, u16* __restrict__ klo,
                u16* __restrict__ vbf) {
    __shared__ __attribute__((aligned(16))) u16 lxh[64][260];
    __shared__ __attribute__((aligned(16))) u16 lxl[64][260];
    const int b  = blockIdx.y;
    const int n0 = blockIdx.x * 64;
    const int t  = threadIdx.x;
    const int w  = t >> 6;
    const int l  = t & 63;
    const int cl = l & 15;
    const int kg = l >> 4;

    const int sn = (t & 15) * 4;
    const int sc = t >> 4;
#pragma unroll
    for (int cc = 0; cc < 16; cc++) {
        const int c = sc + cc * 16;
        const f32x4 xv = *(const f32x4*)&x[((size_t)(b * CDIM + c)) * NTOK + n0 + sn];
#pragma unroll
        for (int i = 0; i < 4; i++) {
            u16 hh = f2bf(xv[i]);
            lxh[sn + i][c] = hh;
            lxl[sn + i][c] = f2bf(xv[i] - bf2f(hh));
        }
    }
    __syncthreads();

    f32x4 acc[5][4];
    const f32x4 fz = {0.f, 0.f, 0.f, 0.f};
#pragma unroll
    for (int i = 0; i < 5; i++)
#pragma unroll
        for (int nt = 0; nt < 4; nt++) acc[i][nt] = fz;

#pragma unroll 2
    for (int ks = 0; ks < 8; ks++) {
        const int k0 = ks * 32;
        short8 bh[4], bl[4];
#pragma unroll
        for (int nt = 0; nt < 4; nt++) {
            bh[nt] = *(const short8*)&lxh[nt * 16 + cl][k0 + kg * 8];
            bl[nt] = *(const short8*)&lxl[nt * 16 + cl][k0 + kg * 8];
        }
#pragma unroll
        for (int i = 0; i < 5; i++) {
            const int mt = w * 5 + i;
            const size_t wb = (size_t)(mt * 16 + cl) * 256 + k0 + kg * 8;
            const short8 ah = *(const short8*)&whi[wb];
            const short8 al = *(const short8*)&wlo[wb];
#pragma unroll
            for (int nt = 0; nt < 4; nt++) {
                acc[i][nt] = __builtin_amdgcn_mfma_f32_16x16x32_bf16(ah, bh[nt], acc[i][nt], 0, 0, 0);
                acc[i][nt] = __builtin_amdgcn_mfma_f32_16x16x32_bf16(ah, bl[nt], acc[i][nt], 0, 0, 0);
                acc[i][nt] = __builtin_amdgcn_mfma_f32_16x16x32_bf16(al, bh[nt], acc[i][nt], 0, 0, 0);
            }
        }
    }

#pragma unroll
    for (int i = 0; i < 5; i++) {
        const int mt = w * 5 + i;
#pragma unroll
        for (int nt = 0; nt < 4; nt++) {
            const int n = n0 + nt * 16 + cl;
#pragma unroll
            for (int r = 0; r < 4; r++) {
                const int m = kg * 4 + r;
                float v = acc[i][nt][r];
                if (mt < 2) {
                    const int ch = mt * 16 + m;
                    v += bq[ch];
                    u16 hh = f2bf(v);
                    qhi[((size_t)(b * NTOK + n)) * 32 + ch] = hh;
                    qlo[((size_t)(b * NTOK + n)) * 32 + ch] = f2bf(v - bf2f(hh));
                } else if (mt < 4) {
                    const int ch = (mt - 2) * 16 + m;
                    v += bk[ch];
                    u16 hh = f2bf(v);
                    khi[((size_t)(b * NTOK + n)) * 32 + ch] = hh;
                    klo[((size_t)(b * NTOK + n)) * 32 + ch] = f2bf(v - bf2f(hh));
                } else {
                    const int c2 = (mt - 4) * 16 + m;
                    vbf[((size_t)(b * CDIM + c2)) * NTOK + n] = f2bf(v + bv[c2]);
                }
            }
        }
    }
}

// ---------------------------------------------------------------------------
// Fused flash attention, TJ=64 (64 keys per iteration, 64 iterations).
// Block = 4 waves, TQ=64 queries, ONE HALF (h) of the 256 channels.
// Wave w: q-tile w (16 q), 128 c. Grid 512 -> 2 independent blocks/CU.
//   St[j][q] = mfma(A=K, B=Q), 3-term hi/lo, 4 j-subtiles (12 MFMAs)
//   one in-lane softmax + 2 shfl + one defer-check per 64 j; 16 exp2
//   P exchange: 4x ds_write_b64 + 2x ds_read_b128 (per-wave buffer)
//   PV: D[c][q] = mfma(A=V, B=P), 2 ks x 8 ct = 16 MFMAs, acc[8] (no spill)
// V LDS rows padded to 72 u16 (144B pitch): bank-uniform w/o XOR swizzle.
// ---------------------------------------------------------------------------
__global__ __launch_bounds__(256, 2)
void attn_mfma(const u16* __restrict__ qhi, const u16* __restrict__ qlo,
               const u16* __restrict__ khi, const u16* __restrict__ klo,
               const u16* __restrict__ vbf, const float* __restrict__ x,
               float* __restrict__ out) {
    __shared__ __attribute__((aligned(16))) u16 lkh[2][TJ][32];
    __shared__ __attribute__((aligned(16))) u16 lkl[2][TJ][32];
    __shared__ __attribute__((aligned(16))) u16 lv[2][128][72];
    __shared__ __attribute__((aligned(16))) u32 lp[4][16][36];
    __shared__ __attribute__((aligned(16))) float lt[4][16][20];

    // XCD decode: (b,h) fixed per XCD -> V-half (1MB) + K resident in that L2
    const int lin = blockIdx.x;
    const int p  = lin & 7;
    const int b  = p >> 1;
    const int h  = p & 1;
    const int qb = lin >> 3;
    const int i0 = qb * TQ;
    const int t  = threadIdx.x;
    const int w  = t >> 6;
    const int l  = t & 63;
    const int cl = l & 15;
    const int kg = l >> 4;

    // Q B-fragments
    const int iq = i0 + w * 16 + cl;
    const short8 qh = *(const short8*)&qhi[((size_t)(b * NTOK + iq)) * 32 + kg * 8];
    const short8 ql = *(const short8*)&qlo[((size_t)(b * NTOK + iq)) * 32 + kg * 8];

    // staging: V half (128 c-rows; thread t -> row t&127, j-half t>>7)
    const int vc    = t & 127;
    const int vhalf = t >> 7;
    const u16* vsrc = &vbf[((size_t)(b * CDIM + h * 128 + vc)) * NTOK + vhalf * 32];
    // K: 64 j-rows x 32 d hi/lo; thread (t&127) -> row (t&127)>>1, 2 chunks
    const int kj   = (t & 127) >> 1;
    const int kch2 = (t & 1) * 2;
    const u16* ksrcbase = (t < 128) ? khi : klo;
    const u16* ksrc = &ksrcbase[((size_t)(b * NTOK + kj)) * 32 + kch2 * 8];

    u16x8 vreg[4];
    u16x8 kreg0, kreg1;

    auto stage_load = [&](int tt) {
        const size_t j0 = (size_t)tt * TJ;
#pragma unroll
        for (int ch = 0; ch < 4; ch++)
            vreg[ch] = *(const u16x8*)&vsrc[j0 + ch * 8];
        kreg0 = *(const u16x8*)&ksrc[j0 * 32];
        kreg1 = *(const u16x8*)&ksrc[j0 * 32 + 8];
    };
    auto stage_write = [&](int buf) {
#pragma unroll
        for (int ch = 0; ch < 4; ch++)
            *(u16x8*)&lv[buf][vc][vhalf * 32 + ch * 8] = vreg[ch];
        const int swk = (kj >> 2) & 3;
        u16* kbase = (t < 128) ? &lkh[buf][kj][0] : &lkl[buf][kj][0];
        *(u16x8*)&kbase[((kch2)     ^ swk) * 8] = kreg0;
        *(u16x8*)&kbase[((kch2 + 1) ^ swk) * 8] = kreg1;
    };

    f32x4 acc[8];   // D[c][q]: local c-row = ct*16 + kg*4 + r, q = cl
    const f32x4 fz = {0.f, 0.f, 0.f, 0.f};
#pragma unroll
    for (int ct = 0; ct < 8; ct++) acc[ct] = fz;

    float m_r = -1.0e30f, l_r = 0.f;   // per-lane partials (reduced at end)

    stage_load(0);
    stage_write(0);
    __syncthreads();

#pragma unroll 2
    for (int tt = 0; tt < NT; ++tt) {
        const int cur = tt & 1;
        const int nxt = cur ^ 1;
        const bool pre = (tt + 1 < NT);
        if (pre) stage_load(tt + 1);   // issue global loads early (T14)

        // ---- scores (swapped): St[j][q], lane q=cl, 4 j-subtiles
        f32x4 s[4];
#pragma unroll
        for (int jt = 0; jt < 4; jt++) {
            const int row = jt * 16 + cl;
            const int ph  = (kg ^ ((row >> 2) & 3)) * 8;
            short8 kh = *(const short8*)&lkh[cur][row][ph];
            short8 kl = *(const short8*)&lkl[cur][row][ph];
            f32x4 sv = fz;
            sv = __builtin_amdgcn_mfma_f32_16x16x32_bf16(kh, qh, sv, 0, 0, 0);
            sv = __builtin_amdgcn_mfma_f32_16x16x32_bf16(kl, qh, sv, 0, 0, 0);
            sv = __builtin_amdgcn_mfma_f32_16x16x32_bf16(kh, ql, sv, 0, 0, 0);
            s[jt] = sv;
        }

        // ---- one in-lane softmax for all 64 j
        float tmax = -1.0e30f;
#pragma unroll
        for (int jt = 0; jt < 4; jt++)
            tmax = fmaxf(tmax, fmaxf(fmaxf(s[jt][0], s[jt][1]), fmaxf(s[jt][2], s[jt][3])));
        tmax = fmaxf(tmax, __shfl_xor(tmax, 16));
        tmax = fmaxf(tmax, __shfl_xor(tmax, 32));

        if (__any(tmax > m_r + 8.f)) {          // defer-max rescale event
            float mn = fmaxf(m_r, tmax);
            float f  = exp2f((m_r - mn) * LOG2E);
            m_r = mn;
            l_r *= f;
#pragma unroll
            for (int ct = 0; ct < 8; ct++) acc[ct] *= f;
        }
        const float mmv = m_r * LOG2E;
        f32x4 pe[4];
#pragma unroll
        for (int jt = 0; jt < 4; jt++) {
#pragma unroll
            for (int r = 0; r < 4; r++)
                pe[jt][r] = exp2f(fmaf(s[jt][r], LOG2E, -mmv));
        }
        float psum = 0.f;
#pragma unroll
        for (int jt = 0; jt < 4; jt++)
            psum += (pe[jt][0] + pe[jt][1]) + (pe[jt][2] + pe[jt][3]);
        l_r += psum;

        // ---- pack + per-wave LDS P-exchange (same-wave, no barrier)
        // lane (cl,kg) holds j = jt*16 + 4kg + {0..3} -> pairs jt*8 + 2kg, +1
#pragma unroll
        for (int jt = 0; jt < 4; jt++) {
            u32x2 wp;
            wp[0] = pk_bf16(pe[jt][0], pe[jt][1]);
            wp[1] = pk_bf16(pe[jt][2], pe[jt][3]);
            *(u32x2*)&lp[w][cl][jt * 8 + 2 * kg] = wp;
        }
        // B-frag lane (cl,kg), half ks: k = kg*8..+7 -> pairs ks*16 + 4kg..+3
        const short8 pf0 = __builtin_bit_cast(short8, *(const u32x4*)&lp[w][cl][4 * kg]);
        const short8 pf1 = __builtin_bit_cast(short8, *(const u32x4*)&lp[w][cl][16 + 4 * kg]);

        // ---- PV: 2 ks x 8 ct (ks outer: 8 independent MFMAs per pass)
#pragma unroll
        for (int ct = 0; ct < 8; ct++) {
            const int row = ct * 16 + cl;
            short8 vb = *(const short8*)&lv[cur][row][kg * 8];
            acc[ct] = __builtin_amdgcn_mfma_f32_16x16x32_bf16(vb, pf0, acc[ct], 0, 0, 0);
        }
#pragma unroll
        for (int ct = 0; ct < 8; ct++) {
            const int row = ct * 16 + cl;
            short8 vb = *(const short8*)&lv[cur][row][32 + kg * 8];
            acc[ct] = __builtin_amdgcn_mfma_f32_16x16x32_bf16(vb, pf1, acc[ct], 0, 0, 0);
        }

        if (pre) stage_write(nxt);
        __syncthreads();
    }

    // ---- reduce l across the 4 lane-groups, then epilogue
    l_r += __shfl_xor(l_r, 16);
    l_r += __shfl_xor(l_r, 32);
    const float linv = 1.f / l_r;
    const int c_r = l >> 2;
    const int q0  = (l & 3) * 4;
#pragma unroll
    for (int ct = 0; ct < 8; ct++) {
#pragma unroll
        for (int r = 0; r < 4; r++)
            lt[w][kg * 4 + r][cl] = acc[ct][r] * linv;
        __syncthreads();
        const f32x4 vv = *(const f32x4*)&lt[w][c_r][q0];
        const int c = h * 128 + ct * 16 + c_r;
        const size_t base = ((size_t)(b * CDIM + c)) * NTOK + i0 + w * 16 + q0;
        const f32x4 xv = *(const f32x4*)&x[base];
        f32x4 o;
#pragma unroll
        for (int ii = 0; ii < 4; ii++) o[ii] = vv[ii] + xv[ii];
        *(f32x4*)&out[base] = o;
        __syncthreads();
    }
}

// ---------------------------------------------------------------------------
extern "C" void kernel_launch(void* const* d_in, const int* in_sizes, int n_in,
                              void* d_out, int out_size, void* d_ws, size_t ws_size,
                              hipStream_t stream) {
    const float* x  = (const float*)d_in[0];
    const float* Wq = (const float*)d_in[1];
    const float* bq = (const float*)d_in[2];
    const float* Wk = (const float*)d_in[3];
    const float* bk = (const float*)d_in[4];
    const float* Wv = (const float*)d_in[5];
    const float* bv = (const float*)d_in[6];
    float* out = (float*)d_out;

    u16* qhi = (u16*)d_ws;                              // [4][4096][32]
    u16* qlo = qhi + (size_t)4 * NTOK * 32;
    u16* khi = qlo + (size_t)4 * NTOK * 32;
    u16* klo = khi + (size_t)4 * NTOK * 32;
    u16* vbf = klo + (size_t)4 * NTOK * 32;             // [4][256][4096]
    u16* whi = vbf + (size_t)4 * CDIM * NTOK;           // [320][256]
    u16* wlo = whi + (size_t)320 * 256;

    wconv<<<dim3(320), 256, 0, stream>>>(Wq, Wk, Wv, whi, wlo);
    proj_fused<<<dim3(64, 4), 256, 0, stream>>>(x, whi, wlo, bq, bk, bv,
                                                qhi, qlo, khi, klo, vbf);
    attn_mfma<<<dim3(512), 256, 0, stream>>>(qhi, qlo, khi, klo, vbf, x, out);
}

// Round 9
// 156.216 us; speedup vs baseline: 2.4235x; 1.0206x over previous
//
#include <hip/hip_runtime.h>

typedef short short8 __attribute__((ext_vector_type(8)));
typedef float f32x4 __attribute__((ext_vector_type(4)));
typedef unsigned short u16;
typedef u16 u16x8 __attribute__((ext_vector_type(8)));
typedef unsigned int u32;
typedef u32 u32x2 __attribute__((ext_vector_type(2)));
typedef u32 u32x4 __attribute__((ext_vector_type(4)));

#define NTOK 4096
#define CDIM 256
#define TQ 64
#define TJ 64
#define NT (NTOK / TJ)
#define LOG2E 1.44269504088896f

__device__ __forceinline__ u16 f2bf(float f) {
    unsigned u = __float_as_uint(f);
    unsigned r = (u + 0x7fffu + ((u >> 16) & 1u)) >> 16;   // RNE
    return (u16)r;
}
__device__ __forceinline__ float bf2f(u16 h) { return __uint_as_float(((unsigned)h) << 16); }
__device__ __forceinline__ u32 pk_bf16(float a, float b) {
    u32 w;
    asm("v_cvt_pk_bf16_f32 %0, %1, %2" : "=v"(w) : "v"(a), "v"(b));
    return w;
}

// ---------------------------------------------------------------------------
// W convert: rows 0-31 Wq, 32-63 Wk, 64-319 Wv -> whi/wlo bf16 [320][256]
// ---------------------------------------------------------------------------
__global__ __launch_bounds__(256)
void wconv(const float* __restrict__ Wq, const float* __restrict__ Wk,
           const float* __restrict__ Wv, u16* __restrict__ whi, u16* __restrict__ wlo) {
    const int row = blockIdx.x;
    const int col = threadIdx.x;
    float v;
    if (row < 32)       v = Wq[row * 256 + col];
    else if (row < 64)  v = Wk[(row - 32) * 256 + col];
    else                v = Wv[(row - 64) * 256 + col];
    u16 h = f2bf(v);
    whi[row * 256 + col] = h;
    wlo[row * 256 + col] = f2bf(v - bf2f(h));
}

// ---------------------------------------------------------------------------
// Fused projection via MFMA (hi/lo 3-term). Block: 64 tokens, all 320 out ch.
// ---------------------------------------------------------------------------
__global__ __launch_bounds__(256, 1)
void proj_fused(const float* __restrict__ x,
                const u16* __restrict__ whi, const u16* __restrict__ wlo,
                const float* __restrict__ bq, const float* __restrict__ bk,
                const float* __restrict__ bv,
                u16* __restrict__ qhi, u16* __restrict__ qlo,
                u16* __restrict__ khi, u16* __restrict__ klo,
                u16* __restrict__ vbf) {
    __shared__ __attribute__((aligned(16))) u16 lxh[64][260];
    __shared__ __attribute__((aligned(16))) u16 lxl[64][260];
    const int b  = blockIdx.y;
    const int n0 = blockIdx.x * 64;
    const int t  = threadIdx.x;
    const int w  = t >> 6;
    const int l  = t & 63;
    const int cl = l & 15;
    const int kg = l >> 4;

    const int sn = (t & 15) * 4;
    const int sc = t >> 4;
#pragma unroll
    for (int cc = 0; cc < 16; cc++) {
        const int c = sc + cc * 16;
        const f32x4 xv = *(const f32x4*)&x[((size_t)(b * CDIM + c)) * NTOK + n0 + sn];
#pragma unroll
        for (int i = 0; i < 4; i++) {
            u16 hh = f2bf(xv[i]);
            lxh[sn + i][c] = hh;
            lxl[sn + i][c] = f2bf(xv[i] - bf2f(hh));
        }
    }
    __syncthreads();

    f32x4 acc[5][4];
    const f32x4 fz = {0.f, 0.f, 0.f, 0.f};
#pragma unroll
    for (int i = 0; i < 5; i++)
#pragma unroll
        for (int nt = 0; nt < 4; nt++) acc[i][nt] = fz;

#pragma unroll 2
    for (int ks = 0; ks < 8; ks++) {
        const int k0 = ks * 32;
        short8 bh[4], bl[4];
#pragma unroll
        for (int nt = 0; nt < 4; nt++) {
            bh[nt] = *(const short8*)&lxh[nt * 16 + cl][k0 + kg * 8];
            bl[nt] = *(const short8*)&lxl[nt * 16 + cl][k0 + kg * 8];
        }
#pragma unroll
        for (int i = 0; i < 5; i++) {
            const int mt = w * 5 + i;
            const size_t wb = (size_t)(mt * 16 + cl) * 256 + k0 + kg * 8;
            const short8 ah = *(const short8*)&whi[wb];
            const short8 al = *(const short8*)&wlo[wb];
#pragma unroll
            for (int nt = 0; nt < 4; nt++) {
                acc[i][nt] = __builtin_amdgcn_mfma_f32_16x16x32_bf16(ah, bh[nt], acc[i][nt], 0, 0, 0);
                acc[i][nt] = __builtin_amdgcn_mfma_f32_16x16x32_bf16(ah, bl[nt], acc[i][nt], 0, 0, 0);
                acc[i][nt] = __builtin_amdgcn_mfma_f32_16x16x32_bf16(al, bh[nt], acc[i][nt], 0, 0, 0);
            }
        }
    }

#pragma unroll
    for (int i = 0; i < 5; i++) {
        const int mt = w * 5 + i;
#pragma unroll
        for (int nt = 0; nt < 4; nt++) {
            const int n = n0 + nt * 16 + cl;
#pragma unroll
            for (int r = 0; r < 4; r++) {
                const int m = kg * 4 + r;
                float v = acc[i][nt][r];
                if (mt < 2) {
                    const int ch = mt * 16 + m;
                    v += bq[ch];
                    u16 hh = f2bf(v);
                    qhi[((size_t)(b * NTOK + n)) * 32 + ch] = hh;
                    qlo[((size_t)(b * NTOK + n)) * 32 + ch] = f2bf(v - bf2f(hh));
                } else if (mt < 4) {
                    const int ch = (mt - 2) * 16 + m;
                    v += bk[ch];
                    u16 hh = f2bf(v);
                    khi[((size_t)(b * NTOK + n)) * 32 + ch] = hh;
                    klo[((size_t)(b * NTOK + n)) * 32 + ch] = f2bf(v - bf2f(hh));
                } else {
                    const int c2 = (mt - 4) * 16 + m;
                    vbf[((size_t)(b * CDIM + c2)) * NTOK + n] = f2bf(v + bv[c2]);
                }
            }
        }
    }
}

// ---------------------------------------------------------------------------
// Fused flash attention, TJ=64, half-tile software pipeline.
// Block = 4 waves, TQ=64 queries, ONE HALF (h) of the 256 channels.
// Each phase: {QK^T(half) || PV(prev half)} then softmax(half) -> P-frag.
// PV is skewed one half-phase so its MFMAs/LDS overlap softmax VALU and the
// next QK^T. 2 barriers/tile. All index math verified in rounds 7-8.
// ---------------------------------------------------------------------------
__global__ __launch_bounds__(256, 2)
void attn_mfma(const u16* __restrict__ qhi, const u16* __restrict__ qlo,
               const u16* __restrict__ khi, const u16* __restrict__ klo,
               const u16* __restrict__ vbf, const float* __restrict__ x,
               float* __restrict__ out) {
    __shared__ __attribute__((aligned(16))) u16 lkh[2][TJ][32];
    __shared__ __attribute__((aligned(16))) u16 lkl[2][TJ][32];
    __shared__ __attribute__((aligned(16))) u16 lv[2][128][72];
    __shared__ __attribute__((aligned(16))) u32 lp[4][16][20];
    __shared__ __attribute__((aligned(16))) float lt[4][16][20];

    // XCD decode: (b,h) fixed per XCD -> V-half (1MB) + K resident in that L2
    const int lin = blockIdx.x;
    const int p  = lin & 7;
    const int b  = p >> 1;
    const int h  = p & 1;
    const int qb = lin >> 3;
    const int i0 = qb * TQ;
    const int t  = threadIdx.x;
    const int w  = t >> 6;
    const int l  = t & 63;
    const int cl = l & 15;
    const int kg = l >> 4;

    // Q B-fragments
    const int iq = i0 + w * 16 + cl;
    const short8 qh = *(const short8*)&qhi[((size_t)(b * NTOK + iq)) * 32 + kg * 8];
    const short8 ql = *(const short8*)&qlo[((size_t)(b * NTOK + iq)) * 32 + kg * 8];

    // staging: V half (128 c-rows; thread t -> row t&127, j-half t>>7)
    const int vc    = t & 127;
    const int vhalf = t >> 7;
    const u16* vsrc = &vbf[((size_t)(b * CDIM + h * 128 + vc)) * NTOK + vhalf * 32];
    // K: 64 j-rows x 32 d hi/lo; thread (t&127) -> row (t&127)>>1, 2 chunks
    const int kj   = (t & 127) >> 1;
    const int kch2 = (t & 1) * 2;
    const u16* ksrcbase = (t < 128) ? khi : klo;
    const u16* ksrc = &ksrcbase[((size_t)(b * NTOK + kj)) * 32 + kch2 * 8];

    u16x8 vreg[4];
    u16x8 kreg0, kreg1;

    auto stage_load = [&](int tt) {
        const size_t j0 = (size_t)tt * TJ;
#pragma unroll
        for (int ch = 0; ch < 4; ch++)
            vreg[ch] = *(const u16x8*)&vsrc[j0 + ch * 8];
        kreg0 = *(const u16x8*)&ksrc[j0 * 32];
        kreg1 = *(const u16x8*)&ksrc[j0 * 32 + 8];
    };
    auto stage_write = [&](int buf) {
#pragma unroll
        for (int ch = 0; ch < 4; ch++)
            *(u16x8*)&lv[buf][vc][vhalf * 32 + ch * 8] = vreg[ch];
        const int swk = (kj >> 2) & 3;
        u16* kbase = (t < 128) ? &lkh[buf][kj][0] : &lkl[buf][kj][0];
        *(u16x8*)&kbase[((kch2)     ^ swk) * 8] = kreg0;
        *(u16x8*)&kbase[((kch2 + 1) ^ swk) * 8] = kreg1;
    };

    f32x4 acc[8];   // D[c][q]: local c-row = ct*16 + kg*4 + r, q = cl
    const f32x4 fz = {0.f, 0.f, 0.f, 0.f};
#pragma unroll
    for (int ct = 0; ct < 8; ct++) acc[ct] = fz;

    float m_r = -1.0e30f, l_r = 0.f;   // per-lane partials (reduced at end)

    // ---- half-tile primitives (index math from verified rounds 7-8) ----
    auto qkt_half = [&](int cur, int jtBase, f32x4& ra, f32x4& rb) {
        {
            const int row = jtBase * 16 + cl;
            const int ph  = (kg ^ ((row >> 2) & 3)) * 8;
            short8 kh = *(const short8*)&lkh[cur][row][ph];
            short8 kl = *(const short8*)&lkl[cur][row][ph];
            f32x4 sv = fz;
            sv = __builtin_amdgcn_mfma_f32_16x16x32_bf16(kh, qh, sv, 0, 0, 0);
            sv = __builtin_amdgcn_mfma_f32_16x16x32_bf16(kl, qh, sv, 0, 0, 0);
            sv = __builtin_amdgcn_mfma_f32_16x16x32_bf16(kh, ql, sv, 0, 0, 0);
            ra = sv;
        }
        {
            const int row = (jtBase + 1) * 16 + cl;
            const int ph  = (kg ^ ((row >> 2) & 3)) * 8;
            short8 kh = *(const short8*)&lkh[cur][row][ph];
            short8 kl = *(const short8*)&lkl[cur][row][ph];
            f32x4 sv = fz;
            sv = __builtin_amdgcn_mfma_f32_16x16x32_bf16(kh, qh, sv, 0, 0, 0);
            sv = __builtin_amdgcn_mfma_f32_16x16x32_bf16(kl, qh, sv, 0, 0, 0);
            sv = __builtin_amdgcn_mfma_f32_16x16x32_bf16(kh, ql, sv, 0, 0, 0);
            rb = sv;
        }
    };
    auto pv_half = [&](int buf, int ksOff, short8 pf) {
#pragma unroll
        for (int ct = 0; ct < 8; ct++) {
            const int row = ct * 16 + cl;
            short8 vb = *(const short8*)&lv[buf][row][ksOff + kg * 8];
            acc[ct] = __builtin_amdgcn_mfma_f32_16x16x32_bf16(vb, pf, acc[ct], 0, 0, 0);
        }
    };
    auto sm_half = [&](f32x4 sa, f32x4 sb) -> short8 {
        float tmax = fmaxf(fmaxf(fmaxf(sa[0], sa[1]), fmaxf(sa[2], sa[3])),
                           fmaxf(fmaxf(sb[0], sb[1]), fmaxf(sb[2], sb[3])));
        tmax = fmaxf(tmax, __shfl_xor(tmax, 16));
        tmax = fmaxf(tmax, __shfl_xor(tmax, 32));
        if (__any(tmax > m_r + 8.f)) {          // defer-max rescale event
            float mn = fmaxf(m_r, tmax);
            float f  = exp2f((m_r - mn) * LOG2E);
            m_r = mn;
            l_r *= f;
#pragma unroll
            for (int ct = 0; ct < 8; ct++) acc[ct] *= f;
        }
        const float mmv = m_r * LOG2E;
        float p0 = exp2f(fmaf(sa[0], LOG2E, -mmv));
        float p1 = exp2f(fmaf(sa[1], LOG2E, -mmv));
        float p2 = exp2f(fmaf(sa[2], LOG2E, -mmv));
        float p3 = exp2f(fmaf(sa[3], LOG2E, -mmv));
        float p4 = exp2f(fmaf(sb[0], LOG2E, -mmv));
        float p5 = exp2f(fmaf(sb[1], LOG2E, -mmv));
        float p6 = exp2f(fmaf(sb[2], LOG2E, -mmv));
        float p7 = exp2f(fmaf(sb[3], LOG2E, -mmv));
        l_r += ((p0 + p1) + (p2 + p3)) + ((p4 + p5) + (p6 + p7));
        u32x2 wA, wB;
        wA[0] = pk_bf16(p0, p1); wA[1] = pk_bf16(p2, p3);
        wB[0] = pk_bf16(p4, p5); wB[1] = pk_bf16(p6, p7);
        *(u32x2*)&lp[w][cl][2 * kg]     = wA;   // pairs for jt_local 0
        *(u32x2*)&lp[w][cl][8 + 2 * kg] = wB;   // pairs for jt_local 1
        return __builtin_bit_cast(short8, *(const u32x4*)&lp[w][cl][4 * kg]);
    };

    short8 pA, pcarry;
    f32x4 sa, sb;

    // ---- prologue: stage tile 0; peel T=0 (no skewed PV in its h0) ----
    stage_load(0);
    stage_write(0);
    __syncthreads();

    stage_load(1);
    qkt_half(0, 0, sa, sb);
    pA = sm_half(sa, sb);
    __syncthreads();                    // mid (uniform shape with main loop)
    stage_write(1);
    __builtin_amdgcn_s_setprio(1);
    qkt_half(0, 2, sa, sb);
    pv_half(0, 0, pA);                  // PV(T=0,h0)
    __builtin_amdgcn_s_setprio(0);
    pcarry = sm_half(sa, sb);
    __syncthreads();                    // end

    // ---- main loop T = 1..62 (branch-free) ----
    for (int tt = 1; tt < NT - 1; ++tt) {
        const int cur = tt & 1;
        const int nxt = cur ^ 1;

        // h0 phase: QK^T(h0) || PV(T-1,h1)
        stage_load(tt + 1);
        __builtin_amdgcn_s_setprio(1);
        qkt_half(cur, 0, sa, sb);
        pv_half(nxt, 32, pcarry);       // V tile T-1 = buf nxt, second half
        __builtin_amdgcn_s_setprio(0);
        pA = sm_half(sa, sb);
        __syncthreads();                // mid: PV reads of lv[nxt] done

        // h1 phase: stage_write || QK^T(h1) || PV(T,h0)
        stage_write(nxt);               // tile T+1 into buf nxt
        __builtin_amdgcn_s_setprio(1);
        qkt_half(cur, 2, sa, sb);
        pv_half(cur, 0, pA);            // V tile T = buf cur, first half
        __builtin_amdgcn_s_setprio(0);
        pcarry = sm_half(sa, sb);
        __syncthreads();                // end: staged tile T+1 visible
    }

    // ---- peel T=63 (no staging) ----
    {
        qkt_half(1, 0, sa, sb);
        pv_half(0, 32, pcarry);         // PV(62,h1)
        pA = sm_half(sa, sb);
        __syncthreads();
        qkt_half(1, 2, sa, sb);
        pv_half(1, 0, pA);              // PV(63,h0)
        pcarry = sm_half(sa, sb);
    }
    pv_half(1, 32, pcarry);             // final PV(63,h1)

    // ---- reduce l across the 4 lane-groups, per-wave transpose epilogue ----
    l_r += __shfl_xor(l_r, 16);
    l_r += __shfl_xor(l_r, 32);
    const float linv = 1.f / l_r;
    const int c_r = l >> 2;
    const int q0  = (l & 3) * 4;
#pragma unroll
    for (int ct = 0; ct < 8; ct++) {
#pragma unroll
        for (int r = 0; r < 4; r++)
            lt[w][kg * 4 + r][cl] = acc[ct][r] * linv;
        // lt[w] is private to wave w; DS ops are in-order per wave -> no barrier
        const f32x4 vv = *(const f32x4*)&lt[w][c_r][q0];
        const int c = h * 128 + ct * 16 + c_r;
        const size_t base = ((size_t)(b * CDIM + c)) * NTOK + i0 + w * 16 + q0;
        const f32x4 xv = *(const f32x4*)&x[base];
        f32x4 o;
#pragma unroll
        for (int ii = 0; ii < 4; ii++) o[ii] = vv[ii] + xv[ii];
        *(f32x4*)&out[base] = o;
    }
}

// ---------------------------------------------------------------------------
extern "C" void kernel_launch(void* const* d_in, const int* in_sizes, int n_in,
                              void* d_out, int out_size, void* d_ws, size_t ws_size,
                              hipStream_t stream) {
    const float* x  = (const float*)d_in[0];
    const float* Wq = (const float*)d_in[1];
    const float* bq = (const float*)d_in[2];
    const float* Wk = (const float*)d_in[3];
    const float* bk = (const float*)d_in[4];
    const float* Wv = (const float*)d_in[5];
    const float* bv = (const float*)d_in[6];
    float* out = (float*)d_out;

    u16* qhi = (u16*)d_ws;                              // [4][4096][32]
    u16* qlo = qhi + (size_t)4 * NTOK * 32;
    u16* khi = qlo + (size_t)4 * NTOK * 32;
    u16* klo = khi + (size_t)4 * NTOK * 32;
    u16* vbf = klo + (size_t)4 * NTOK * 32;             // [4][256][4096]
    u16* whi = vbf + (size_t)4 * CDIM * NTOK;           // [320][256]
    u16* wlo = whi + (size_t)320 * 256;

    wconv<<<dim3(320), 256, 0, stream>>>(Wq, Wk, Wv, whi, wlo);
    proj_fused<<<dim3(64, 4), 256, 0, stream>>>(x, whi, wlo, bq, bk, bv,
                                                qhi, qlo, khi, klo, vbf);
    attn_mfma<<<dim3(512), 256, 0, stream>>>(qhi, qlo, khi, klo, vbf, x, out);
}